// Round 6
// baseline (47.169 us; speedup 1.0000x reference)
//
#include <hip/hip_runtime.h>
#include <math.h>

#define BB_ 512
#define NN_ 128
#define DD_ 64
#define NE_ 6
#define NB_ 4

// f32 workspace layout (floats)
#define WS_PAIRE 0    // 144
#define WS_AE    144  // 6
#define WS_ENT   152  // 6
#define WS_TS    160                    // 128*6*256 stability layer1 table
#define WS_TD    (160 + 128 * 6 * 256)  // druglikeness layer1 table

// ---------------------------------------------------------------------------
__device__ __forceinline__ float block_reduce256(float v, volatile float* red4,
                                                 int tid) {
#pragma unroll
  for (int off = 32; off > 0; off >>= 1) v += __shfl_down(v, off);
  __syncthreads();
  if ((tid & 63) == 0) red4[tid >> 6] = v;
  __syncthreads();
  return red4[0] + red4[1] + red4[2] + red4[3];
}

// ---------------------------------------------------------------------------
// k_pre: blk 0..511   -> f32 layer1 tables (n=blk>>2, which=(blk>>1)&1, ohalf)
//        blk 512      -> zero out[0..1024)
//        blk 513..656 -> pairE entries
//        blk 657      -> ae/ent tables
// ---------------------------------------------------------------------------
__global__ __launch_bounds__(256, 4) void k_pre(
    const float* __restrict__ emb, const float* __restrict__ ae_w,
    const float* __restrict__ ae_b, const float* __restrict__ ent_w,
    const float* __restrict__ ent_b, const float* __restrict__ bW,
    const float* __restrict__ sW1, const float* __restrict__ dW1,
    float* __restrict__ ws, float* __restrict__ out) {
  int blk = blockIdx.x;
  int tid = threadIdx.x;

  if (blk < 512) {
    int n = blk >> 2;
    int which = (blk >> 1) & 1;
    int ohalf = blk & 1;
    const float* W1 = which ? dW1 : sW1;
    float* T = ws + (which ? WS_TD : WS_TS);
    __shared__ float e_s[NE_ * DD_];
    __shared__ float part[NE_][128];
    for (int i = tid; i < NE_ * DD_; i += 256) e_s[i] = emb[i];
    __syncthreads();
    int o_local = tid & 127;
    int dhalf = tid >> 7;
    int o = ohalf * 128 + o_local;
    float acc[NE_] = {0.f, 0.f, 0.f, 0.f, 0.f, 0.f};
    const float* Wp = W1 + ((size_t)(n * DD_ + dhalf * 32)) * 256 + o;
#pragma unroll 8
    for (int d = 0; d < 32; ++d) {
      float w = Wp[(size_t)d * 256];
#pragma unroll
      for (int t = 0; t < NE_; ++t) acc[t] += e_s[t * DD_ + dhalf * 32 + d] * w;
    }
    if (dhalf == 1) {
#pragma unroll
      for (int t = 0; t < NE_; ++t) part[t][o_local] = acc[t];
    }
    __syncthreads();
    if (dhalf == 0) {
#pragma unroll
      for (int t = 0; t < NE_; ++t)
        T[(n * NE_ + t) * 256 + o] = acc[t] + part[t][o_local];
    }
  } else if (blk == 512) {
    float4 z = make_float4(0.f, 0.f, 0.f, 0.f);
    ((float4*)out)[tid] = z;  // out[0..1024): energy+entropy accumulators
  } else if (blk < 657) {
    int e = blk - 513;
    int k = e / 36;
    int rem = e - k * 36;
    int ti = rem / 6, tj = rem - (rem / 6) * 6;
    int d = tid & 63;
    int qd = tid >> 6;
    const float* Wrow = bW + ((size_t)k * DD_ + d) * DD_ + qd * 16;
    const float* xj = emb + tj * DD_ + qd * 16;
    float a = 0.f;
#pragma unroll
    for (int u = 0; u < 16; ++u) a += Wrow[u] * xj[u];
    float c = emb[ti * DD_ + d] * a;
    __shared__ float red4[4];
    c = block_reduce256(c, red4, tid);
    if (tid == 0) ws[WS_PAIRE + e] = c;
  } else {
    int g = tid >> 6, lane = tid & 63;
    for (int idx = g; idx < 12; idx += 4) {
      int t = idx - (idx >= 6 ? 6 : 0);
      bool ent = idx >= 6;
      float c = emb[t * DD_ + lane] * (ent ? ent_w[lane] : ae_w[lane]);
#pragma unroll
      for (int off = 32; off > 0; off >>= 1) c += __shfl_down(c, off);
      if (lane == 0)
        ws[(ent ? WS_ENT : WS_AE) + t] = c + (ent ? ent_b[0] : ae_b[0]);
    }
  }
}

// ---------------------------------------------------------------------------
// k_main: 4096 blocks. m = id>>3 (molecule), s = id&7 (slot, interleaved):
//   s=0,1 : bonds half        s=2,3 : vdW half
//   s=4   : variance + linear atomic terms
//   s=5   : x-write           s=6,7 : stability / druglikeness MLP
// ---------------------------------------------------------------------------
__global__ __launch_bounds__(256, 4) void k_main(
    const int* __restrict__ atom_types, const float* __restrict__ pos,
    const int* __restrict__ bonds, const float* __restrict__ emb,
    const float* __restrict__ bb, const float* __restrict__ sb1,
    const float* __restrict__ sW2, const float* __restrict__ sb2,
    const float* __restrict__ sW3, const float* __restrict__ sb3,
    const float* __restrict__ db1, const float* __restrict__ dW2,
    const float* __restrict__ db2, const float* __restrict__ dW3,
    const float* __restrict__ db3, const float* __restrict__ ws,
    float* __restrict__ out) {
  int id = blockIdx.x;
  int m = id >> 3;
  int s = id & 7;
  int tid = threadIdx.x;
  __shared__ float smem[1040];
  volatile float* red4 = smem + 1024;

  if (s < 2) {
    // ---------------- bonds half ----------------
    int h = s;
    unsigned char* tyb = (unsigned char*)smem;  // 128 bytes
    float* pE = smem + 32;                      // 144
    float* bbv = smem + 176;                    // 4
    // hoisted guarded loads (overlap staging)
    const int4* b4 = (const int4*)(bonds + (size_t)m * NN_ * NN_);
    int4 bv[8];
    int bii[8];
    bool hv[8];
#pragma unroll
    for (int it = 0; it < 8; ++it) {
      int li = tid + (it << 8);
      int r = li >> 5;
      int ii = (r < 32) ? (h * 32 + r) : (96 - h * 32 + (r - 32));
      int c = li & 31;
      bii[it] = ii;
      hv[it] = (c * 4 + 3 > ii);
      if (hv[it]) bv[it] = b4[ii * 32 + c];
    }
    if (tid < 32) {
      int4 t4 = ((const int4*)(atom_types + (size_t)m * NN_))[tid];
      uchar4 u4;
      u4.x = (unsigned char)t4.x;
      u4.y = (unsigned char)t4.y;
      u4.z = (unsigned char)t4.z;
      u4.w = (unsigned char)t4.w;
      ((uchar4*)tyb)[tid] = u4;
    }
    if (tid >= 64 && tid < 208) pE[tid - 64] = ws[WS_PAIRE + tid - 64];
    if (tid >= 224 && tid < 228) bbv[tid - 224] = bb[tid - 224];
    __syncthreads();
    float bp = 0.f;
#pragma unroll
    for (int it = 0; it < 8; ++it) {
      if (hv[it]) {
        int ii = bii[it];
        int li = tid + (it << 8);
        int j0 = (li & 31) << 2;
        int4 v = bv[it];
        int ti6 = tyb[ii] * 6;
        if (j0 + 0 > ii && v.x > 0)
          bp += pE[(v.x - 1) * 36 + ti6 + tyb[j0 + 0]] + bbv[v.x - 1];
        if (j0 + 1 > ii && v.y > 0)
          bp += pE[(v.y - 1) * 36 + ti6 + tyb[j0 + 1]] + bbv[v.y - 1];
        if (j0 + 2 > ii && v.z > 0)
          bp += pE[(v.z - 1) * 36 + ti6 + tyb[j0 + 2]] + bbv[v.z - 1];
        if (j0 + 3 > ii && v.w > 0)
          bp += pE[(v.w - 1) * 36 + ti6 + tyb[j0 + 3]] + bbv[v.w - 1];
      }
    }
    float e = block_reduce256(bp, red4, tid);
    if (tid == 0) atomicAdd(&out[m], e);
  } else if (s < 4) {
    // ---------------- vdW half ----------------
    int h = s - 2;
    float4* p4 = (float4*)smem;  // 128 float4
    if (tid < 128) {
      const float* pm = pos + (size_t)m * NN_ * 3 + 3 * tid;
      p4[tid] = make_float4(pm[0], pm[1], pm[2], 0.f);
    }
    __syncthreads();
    int r = tid >> 2;
    int i = (r < 32) ? (h * 32 + r) : (96 - h * 32 + (r - 32));
    float4 pi = p4[i];
    float vp = 0.f;
    int jb = tid & 3;
#pragma unroll 8
    for (int it = 0; it < 32; ++it) {
      int j = jb + (it << 2);
      float4 pj = p4[j];
      float dx = pi.x - pj.x;
      float dy = pi.y - pj.y;
      float dz = pi.z - pj.z;
      float d2 = dx * dx + dy * dy + dz * dz;
      if (j > i && d2 > 0.f) {
        float rc = __builtin_amdgcn_rcpf(d2);
        float r6 = rc * rc * rc;
        vp += 0.4f * (r6 * r6 - r6);
      }
    }
    float e = block_reduce256(vp, red4, tid);
    if (tid == 0) atomicAdd(&out[m], e);
  } else if (s == 4) {
    // ---------------- variance + linear terms ----------------
    float* aev = smem;       // 6
    float* entv = smem + 8;  // 6
    if (tid < NE_) {
      aev[tid] = ws[WS_AE + tid];
      entv[tid] = ws[WS_ENT + tid];
    }
    __syncthreads();
    float x = 0.f, y = 0.f, z = 0.f, sq = 0.f, ae = 0.f, en = 0.f;
    if (tid < 128) {
      const float* pm = pos + (size_t)m * NN_ * 3 + 3 * tid;
      x = pm[0];
      y = pm[1];
      z = pm[2];
      sq = x * x + y * y + z * z;
      int t = atom_types[(size_t)m * NN_ + tid];
      ae = aev[t];
      en = entv[t];
    }
    float Sx = block_reduce256(x, red4, tid);
    float Sy = block_reduce256(y, red4, tid);
    float Sz = block_reduce256(z, red4, tid);
    float Ssq = block_reduce256(sq, red4, tid);
    float Sae = block_reduce256(ae, red4, tid);
    float Sen = block_reduce256(en, red4, tid);
    if (tid == 0) {
      float var =
          (Ssq - (Sx * Sx + Sy * Sy + Sz * Sz) * (1.f / NN_)) * (1.f / (NN_ - 1));
      atomicAdd(&out[m], Sae);
      atomicAdd(&out[BB_ + m], Sen + logf(1.f + var));
    }
  } else if (s == 5) {
    // ---------------- x-write ----------------
    float* e_s = smem;  // 384
    unsigned char* tyb = (unsigned char*)(smem + 384);
    for (int i = tid; i < NE_ * DD_; i += 256) e_s[i] = emb[i];
    if (tid < 32) {
      int4 t4 = ((const int4*)(atom_types + (size_t)m * NN_))[tid];
      uchar4 u4;
      u4.x = (unsigned char)t4.x;
      u4.y = (unsigned char)t4.y;
      u4.z = (unsigned char)t4.z;
      u4.w = (unsigned char)t4.w;
      ((uchar4*)tyb)[tid] = u4;
    }
    __syncthreads();
    float4* out4 = (float4*)(out + 2048 + (size_t)m * (NN_ * DD_));
#pragma unroll
    for (int u = 0; u < 8; ++u) {
      int li = tid + (u << 8);
      int n = li >> 4;
      int d0 = (li & 15) << 2;
      out4[li] = *(const float4*)&e_s[tyb[n] * DD_ + d0];
    }
  } else {
    // ---------------- MLP head ----------------
    int which = s - 6;
    int* roff = (int*)smem;      // 128
    float* h1 = smem + 128;      // 256
    float* h2 = smem + 384;      // 128
    float* rd = smem + 512;      // 256
    if (tid < 128)
      roff[tid] = (tid * NE_ + atom_types[(size_t)m * NN_ + tid]) << 8;
    __syncthreads();

    // layer 1: 128 gathers from L2-resident f32 table, 32-wide batched
    {
      const float* Tb = ws + (which ? WS_TD : WS_TS) + tid;
      float acc = (which ? db1 : sb1)[tid];
#pragma unroll
      for (int n0 = 0; n0 < NN_; n0 += 32) {
        float v[32];
#pragma unroll
        for (int u = 0; u < 32; ++u) v[u] = Tb[roff[n0 + u]];
        float s0 = 0.f, s1 = 0.f, s2 = 0.f, s3 = 0.f;
#pragma unroll
        for (int u = 0; u < 32; u += 4) {
          s0 += v[u];
          s1 += v[u + 1];
          s2 += v[u + 2];
          s3 += v[u + 3];
        }
        acc += (s0 + s1) + (s2 + s3);
      }
      h1[tid] = fmaxf(acc, 0.f);
    }
    __syncthreads();

    // layer 2: split-K over 2 halves, 32-wide batched
    {
      const float* W2 = which ? dW2 : sW2;
      int k = tid & 127, hh = tid >> 7;
      const float* Wp = W2 + (size_t)(hh * 128) * 128 + k;
      const float* h1p = h1 + hh * 128;
      float a2 = 0.f;
#pragma unroll
      for (int o0 = 0; o0 < 128; o0 += 32) {
        float w[32];
#pragma unroll
        for (int u = 0; u < 32; ++u) w[u] = Wp[(size_t)(o0 + u) * 128];
        float s0 = 0.f;
#pragma unroll
        for (int u = 0; u < 32; ++u) s0 += h1p[o0 + u] * w[u];
        a2 += s0;
      }
      rd[tid] = a2;
    }
    __syncthreads();
    if (tid < 128)
      h2[tid] = fmaxf((which ? db2 : sb2)[tid] + rd[tid] + rd[tid + 128], 0.f);
    __syncthreads();
    {
      float p = (tid < 128) ? h2[tid] * (which ? dW3 : sW3)[tid] : 0.f;
      float sres = block_reduce256(p, red4, tid);
      if (tid == 0) {
        float b3 = (which ? db3 : sb3)[0];
        out[(2 + which) * BB_ + m] = 1.f / (1.f + __expf(-(sres + b3)));
      }
    }
  }
}

// ---------------------------------------------------------------------------
extern "C" void kernel_launch(void* const* d_in, const int* in_sizes, int n_in,
                              void* d_out, int out_size, void* d_ws,
                              size_t ws_size, hipStream_t stream) {
  const int* atom_types = (const int*)d_in[0];
  const float* positions = (const float*)d_in[1];
  const int* bonds = (const int*)d_in[2];
  const float* emb = (const float*)d_in[3];
  const float* ae_w = (const float*)d_in[4];
  const float* ae_b = (const float*)d_in[5];
  const float* ent_w = (const float*)d_in[6];
  const float* ent_b = (const float*)d_in[7];
  const float* bW = (const float*)d_in[8];
  const float* bb = (const float*)d_in[9];
  const float* sW1 = (const float*)d_in[10];
  const float* sb1 = (const float*)d_in[11];
  const float* sW2 = (const float*)d_in[12];
  const float* sb2 = (const float*)d_in[13];
  const float* sW3 = (const float*)d_in[14];
  const float* sb3 = (const float*)d_in[15];
  const float* dW1 = (const float*)d_in[16];
  const float* db1 = (const float*)d_in[17];
  const float* dW2 = (const float*)d_in[18];
  const float* db2 = (const float*)d_in[19];
  const float* dW3 = (const float*)d_in[20];
  const float* db3 = (const float*)d_in[21];
  float* out = (float*)d_out;
  float* ws = (float*)d_ws;

  hipLaunchKernelGGL(k_pre, dim3(658), dim3(256), 0, stream, emb, ae_w, ae_b,
                     ent_w, ent_b, bW, sW1, dW1, ws, out);
  hipLaunchKernelGGL(k_main, dim3(4096), dim3(256), 0, stream, atom_types,
                     positions, bonds, emb, bb, sb1, sW2, sb2, sW3, sb3, db1,
                     dW2, db2, dW3, db3, ws, out);
}

// Round 7
// 34.477 us; speedup vs baseline: 1.3682x; 1.3682x over previous
//
#include <hip/hip_runtime.h>
#include <math.h>

#define BB_ 512
#define NN_ 128
#define DD_ 64
#define NE_ 6
#define NB_ 4

// f32 workspace layout (floats)
#define WS_PAIRE 0    // 144
#define WS_AE    144  // 6
#define WS_ENT   152  // 6
#define WS_TS    160                    // 128*6*256 stability layer1 table
#define WS_TD    (160 + 128 * 6 * 256)  // druglikeness layer1 table

// ---------------------------------------------------------------------------
__device__ __forceinline__ float block_reduce256(float v, volatile float* red4,
                                                 int tid) {
#pragma unroll
  for (int off = 32; off > 0; off >>= 1) v += __shfl_down(v, off);
  __syncthreads();
  if ((tid & 63) == 0) red4[tid >> 6] = v;
  __syncthreads();
  return red4[0] + red4[1] + red4[2] + red4[3];
}

// ---------------------------------------------------------------------------
// k_pre: blk 0..511   -> f32 layer1 tables (n=blk>>2, which=(blk>>1)&1, ohalf)
//        blk 512      -> zero out[0..1024)
//        blk 513..656 -> pairE entries
//        blk 657      -> ae/ent tables
// ---------------------------------------------------------------------------
__global__ __launch_bounds__(256, 4) void k_pre(
    const float* __restrict__ emb, const float* __restrict__ ae_w,
    const float* __restrict__ ae_b, const float* __restrict__ ent_w,
    const float* __restrict__ ent_b, const float* __restrict__ bW,
    const float* __restrict__ sW1, const float* __restrict__ dW1,
    float* __restrict__ ws, float* __restrict__ out) {
  int blk = blockIdx.x;
  int tid = threadIdx.x;

  if (blk < 512) {
    int n = blk >> 2;
    int which = (blk >> 1) & 1;
    int ohalf = blk & 1;
    const float* W1 = which ? dW1 : sW1;
    float* T = ws + (which ? WS_TD : WS_TS);
    __shared__ float e_s[NE_ * DD_];
    __shared__ float part[NE_][128];
    for (int i = tid; i < NE_ * DD_; i += 256) e_s[i] = emb[i];
    __syncthreads();
    int o_local = tid & 127;
    int dhalf = tid >> 7;
    int o = ohalf * 128 + o_local;
    float acc[NE_] = {0.f, 0.f, 0.f, 0.f, 0.f, 0.f};
    const float* Wp = W1 + ((size_t)(n * DD_ + dhalf * 32)) * 256 + o;
#pragma unroll 8
    for (int d = 0; d < 32; ++d) {
      float w = Wp[(size_t)d * 256];
#pragma unroll
      for (int t = 0; t < NE_; ++t) acc[t] += e_s[t * DD_ + dhalf * 32 + d] * w;
    }
    if (dhalf == 1) {
#pragma unroll
      for (int t = 0; t < NE_; ++t) part[t][o_local] = acc[t];
    }
    __syncthreads();
    if (dhalf == 0) {
#pragma unroll
      for (int t = 0; t < NE_; ++t)
        T[(n * NE_ + t) * 256 + o] = acc[t] + part[t][o_local];
    }
  } else if (blk == 512) {
    float4 z = make_float4(0.f, 0.f, 0.f, 0.f);
    ((float4*)out)[tid] = z;  // out[0..1024): energy+entropy accumulators
  } else if (blk < 657) {
    int e = blk - 513;
    int k = e / 36;
    int rem = e - k * 36;
    int ti = rem / 6, tj = rem - (rem / 6) * 6;
    int d = tid & 63;
    int qd = tid >> 6;
    const float* Wrow = bW + ((size_t)k * DD_ + d) * DD_ + qd * 16;
    const float* xj = emb + tj * DD_ + qd * 16;
    float a = 0.f;
#pragma unroll
    for (int u = 0; u < 16; ++u) a += Wrow[u] * xj[u];
    float c = emb[ti * DD_ + d] * a;
    __shared__ float red4[4];
    c = block_reduce256(c, red4, tid);
    if (tid == 0) ws[WS_PAIRE + e] = c;
  } else {
    int g = tid >> 6, lane = tid & 63;
    for (int idx = g; idx < 12; idx += 4) {
      int t = idx - (idx >= 6 ? 6 : 0);
      bool ent = idx >= 6;
      float c = emb[t * DD_ + lane] * (ent ? ent_w[lane] : ae_w[lane]);
#pragma unroll
      for (int off = 32; off > 0; off >>= 1) c += __shfl_down(c, off);
      if (lane == 0)
        ws[(ent ? WS_ENT : WS_AE) + t] = c + (ent ? ent_b[0] : ae_b[0]);
    }
  }
}

// ---------------------------------------------------------------------------
// k_main: 1664 blocks.
//   [0,128)     : MLP, 8 molecules/block (which=id&1, grp=id>>1)
//   [128,640)   : bonds, one molecule/block
//   [640,1152)  : vdW + variance + linear terms
//   [1152,1664) : x-write
// ---------------------------------------------------------------------------
__global__ __launch_bounds__(256, 4) void k_main(
    const int* __restrict__ atom_types, const float* __restrict__ pos,
    const int* __restrict__ bonds, const float* __restrict__ emb,
    const float* __restrict__ bb, const float* __restrict__ sb1,
    const float* __restrict__ sW2, const float* __restrict__ sb2,
    const float* __restrict__ sW3, const float* __restrict__ sb3,
    const float* __restrict__ db1, const float* __restrict__ dW2,
    const float* __restrict__ db2, const float* __restrict__ dW3,
    const float* __restrict__ db3, const float* __restrict__ ws,
    float* __restrict__ out) {
  int id = blockIdx.x;
  int tid = threadIdx.x;
  __shared__ float smem[3344];
  volatile float* red4 = smem + 3336;

  if (id < 128) {
    // ================= MLP: 8 molecules =================
    int which = id & 1;
    int mbase = (id >> 1) * 8;
    unsigned char* tyb = (unsigned char*)smem;  // [8][128] bytes
    float* h1 = smem + 256;                     // [8][256]
    float* h2 = smem + 2304;                    // [8][128]

    for (int u = tid; u < 8 * NN_; u += 256)
      tyb[u] = (unsigned char)atom_types[(size_t)mbase * NN_ + u];
    __syncthreads();

    // ---- layer 1: thread = (molecule mi, o-octet ot)
    {
      int mi = tid >> 5;
      int ot = tid & 31;
      const float* Tbase = ws + (which ? WS_TD : WS_TS) + ot * 8;
      const unsigned char* ty = tyb + mi * NN_;
      float4 a0 = make_float4(0.f, 0.f, 0.f, 0.f);
      float4 a1 = a0;
      for (int n0 = 0; n0 < NN_; n0 += 8) {
        float4 v0[8], v1[8];
#pragma unroll
        for (int u = 0; u < 8; ++u) {
          const float* row = Tbase + (((n0 + u) * 6 + (int)ty[n0 + u]) << 8);
          v0[u] = *(const float4*)row;
          v1[u] = *(const float4*)(row + 4);
        }
#pragma unroll
        for (int u = 0; u < 8; ++u) {
          a0.x += v0[u].x; a0.y += v0[u].y; a0.z += v0[u].z; a0.w += v0[u].w;
          a1.x += v1[u].x; a1.y += v1[u].y; a1.z += v1[u].z; a1.w += v1[u].w;
        }
      }
      const float* b1 = (which ? db1 : sb1) + ot * 8;
      float4 bb0 = *(const float4*)b1;
      float4 bb1 = *(const float4*)(b1 + 4);
      float* hp = h1 + mi * 256 + ot * 8;
      hp[0] = fmaxf(a0.x + bb0.x, 0.f);
      hp[1] = fmaxf(a0.y + bb0.y, 0.f);
      hp[2] = fmaxf(a0.z + bb0.z, 0.f);
      hp[3] = fmaxf(a0.w + bb0.w, 0.f);
      hp[4] = fmaxf(a1.x + bb1.x, 0.f);
      hp[5] = fmaxf(a1.y + bb1.y, 0.f);
      hp[6] = fmaxf(a1.z + bb1.z, 0.f);
      hp[7] = fmaxf(a1.w + bb1.w, 0.f);
    }
    __syncthreads();

    // ---- layer 2: thread = (k, o-half), W2 regs reused across 8 molecules
    {
      int k = tid & 127;
      int kh = tid >> 7;
      const float* W2p =
          (which ? dW2 : sW2) + (size_t)(kh * 128) * 128 + k;
      float acc[8] = {0.f, 0.f, 0.f, 0.f, 0.f, 0.f, 0.f, 0.f};
      for (int o0 = 0; o0 < 128; o0 += 16) {
        float w[16];
#pragma unroll
        for (int u = 0; u < 16; ++u) w[u] = W2p[(size_t)(o0 + u) << 7];
#pragma unroll
        for (int mm = 0; mm < 8; ++mm) {
          const float4* hq = (const float4*)(h1 + mm * 256 + kh * 128 + o0);
          float4 q0 = hq[0], q1 = hq[1], q2 = hq[2], q3 = hq[3];
          acc[mm] += q0.x * w[0] + q0.y * w[1] + q0.z * w[2] + q0.w * w[3] +
                     q1.x * w[4] + q1.y * w[5] + q1.z * w[6] + q1.w * w[7] +
                     q2.x * w[8] + q2.y * w[9] + q2.z * w[10] + q2.w * w[11] +
                     q3.x * w[12] + q3.y * w[13] + q3.z * w[14] + q3.w * w[15];
        }
      }
      __syncthreads();  // h1 reads done; reuse h1 as scratch
      float* scr = h1;
#pragma unroll
      for (int mm = 0; mm < 8; ++mm) scr[kh * 1024 + mm * 128 + k] = acc[mm];
      __syncthreads();
      if (tid < 128) {
        float b2v = (which ? db2 : sb2)[tid];
#pragma unroll
        for (int mm = 0; mm < 8; ++mm)
          h2[mm * 128 + tid] = fmaxf(
              b2v + scr[mm * 128 + tid] + scr[1024 + mm * 128 + tid], 0.f);
      }
      __syncthreads();
    }

    // ---- layer 3: 8 parallel 32-lane reductions
    {
      int mm = tid >> 5;
      int ln = tid & 31;
      const float* W3 = which ? dW3 : sW3;
      float s = 0.f;
#pragma unroll
      for (int u = 0; u < 4; ++u) {
        int kk = ln + (u << 5);
        s += h2[mm * 128 + kk] * W3[kk];
      }
#pragma unroll
      for (int off = 16; off > 0; off >>= 1) s += __shfl_down(s, off, 32);
      if (ln == 0) {
        float b3 = (which ? db3 : sb3)[0];
        out[(2 + which) * BB_ + mbase + mm] = 1.f / (1.f + __expf(-(s + b3)));
      }
    }
  } else if (id < 640) {
    // ================= bonds, full molecule =================
    int m = id - 128;
    float* pE = smem;                                  // 144
    float* bbv = smem + 144;                           // 4
    unsigned char* tyb = (unsigned char*)(smem + 160); // 128 B

    if (tid < 32) {
      int4 t4 = ((const int4*)(atom_types + (size_t)m * NN_))[tid];
      uchar4 u4;
      u4.x = (unsigned char)t4.x;
      u4.y = (unsigned char)t4.y;
      u4.z = (unsigned char)t4.z;
      u4.w = (unsigned char)t4.w;
      ((uchar4*)tyb)[tid] = u4;
    }
    if (tid >= 64 && tid < 208) pE[tid - 64] = ws[WS_PAIRE + tid - 64];
    if (tid >= 224 && tid < 228) bbv[tid - 224] = bb[tid - 224];
    __syncthreads();

    const int4* b4 = (const int4*)(bonds + (size_t)m * NN_ * NN_);
    float bp = 0.f;
#pragma unroll 4
    for (int it = 0; it < 16; ++it) {
      int li = tid + (it << 8);
      int i = li >> 5;
      int c = li & 31;
      if (c * 4 + 3 > i) {
        int4 v = b4[li];
        int j0 = c << 2;
        int ti6 = tyb[i] * 6;
        if (j0 + 0 > i && v.x > 0)
          bp += pE[(v.x - 1) * 36 + ti6 + tyb[j0 + 0]] + bbv[v.x - 1];
        if (j0 + 1 > i && v.y > 0)
          bp += pE[(v.y - 1) * 36 + ti6 + tyb[j0 + 1]] + bbv[v.y - 1];
        if (j0 + 2 > i && v.z > 0)
          bp += pE[(v.z - 1) * 36 + ti6 + tyb[j0 + 2]] + bbv[v.z - 1];
        if (j0 + 3 > i && v.w > 0)
          bp += pE[(v.w - 1) * 36 + ti6 + tyb[j0 + 3]] + bbv[v.w - 1];
      }
    }
    float e = block_reduce256(bp, red4, tid);
    if (tid == 0) atomicAdd(&out[m], e);
  } else if (id < 1152) {
    // ================= vdW + variance + linear =================
    int m = id - 640;
    float4* p4 = (float4*)smem;  // 128 float4 = 512 f
    float* aev = smem + 520;
    float* entv = smem + 528;
    if (tid < 128) {
      const float* pm = pos + (size_t)m * NN_ * 3 + 3 * tid;
      p4[tid] = make_float4(pm[0], pm[1], pm[2], 0.f);
    }
    if (tid >= 128 && tid < 128 + NE_) aev[tid - 128] = ws[WS_AE + tid - 128];
    if (tid >= 160 && tid < 160 + NE_) entv[tid - 160] = ws[WS_ENT + tid - 160];
    __syncthreads();

    int i = tid >> 1;
    int half = tid & 1;
    float4 pi = p4[i];
    float vp = 0.f;
#pragma unroll 8
    for (int u = 0; u < 64; ++u) {
      int j = (half << 6) + u;
      float4 pj = p4[j];
      float dx = pi.x - pj.x;
      float dy = pi.y - pj.y;
      float dz = pi.z - pj.z;
      float d2 = dx * dx + dy * dy + dz * dz;
      if (j > i && d2 > 0.f) {
        float rc = __builtin_amdgcn_rcpf(d2);
        float r6 = rc * rc * rc;
        vp += 0.4f * (r6 * r6 - r6);
      }
    }

    float x = 0.f, y = 0.f, z = 0.f, sq = 0.f, ae = 0.f, en = 0.f;
    if (tid < 128) {
      float4 p = p4[tid];
      x = p.x;
      y = p.y;
      z = p.z;
      sq = x * x + y * y + z * z;
      int t = atom_types[(size_t)m * NN_ + tid];
      ae = aev[t];
      en = entv[t];
    }
    float Sv = block_reduce256(vp, red4, tid);
    float Sx = block_reduce256(x, red4, tid);
    float Sy = block_reduce256(y, red4, tid);
    float Sz = block_reduce256(z, red4, tid);
    float Ssq = block_reduce256(sq, red4, tid);
    float Sae = block_reduce256(ae, red4, tid);
    float Sen = block_reduce256(en, red4, tid);
    if (tid == 0) {
      float var = (Ssq - (Sx * Sx + Sy * Sy + Sz * Sz) * (1.f / NN_)) *
                  (1.f / (NN_ - 1));
      atomicAdd(&out[m], Sv + Sae);
      out[BB_ + m] = Sen + logf(1.f + var);  // single writer
    }
  } else {
    // ================= x-write =================
    int m = id - 1152;
    float* e_s = smem;  // 384
    unsigned char* tyb = (unsigned char*)(smem + 384);
    for (int i = tid; i < NE_ * DD_; i += 256) e_s[i] = emb[i];
    if (tid < 32) {
      int4 t4 = ((const int4*)(atom_types + (size_t)m * NN_))[tid];
      uchar4 u4;
      u4.x = (unsigned char)t4.x;
      u4.y = (unsigned char)t4.y;
      u4.z = (unsigned char)t4.z;
      u4.w = (unsigned char)t4.w;
      ((uchar4*)tyb)[tid] = u4;
    }
    __syncthreads();
    float4* out4 = (float4*)(out + 2048 + (size_t)m * (NN_ * DD_));
#pragma unroll
    for (int u = 0; u < 8; ++u) {
      int li = tid + (u << 8);
      int n = li >> 4;
      int d0 = (li & 15) << 2;
      out4[li] = *(const float4*)&e_s[tyb[n] * DD_ + d0];
    }
  }
}

// ---------------------------------------------------------------------------
extern "C" void kernel_launch(void* const* d_in, const int* in_sizes, int n_in,
                              void* d_out, int out_size, void* d_ws,
                              size_t ws_size, hipStream_t stream) {
  const int* atom_types = (const int*)d_in[0];
  const float* positions = (const float*)d_in[1];
  const int* bonds = (const int*)d_in[2];
  const float* emb = (const float*)d_in[3];
  const float* ae_w = (const float*)d_in[4];
  const float* ae_b = (const float*)d_in[5];
  const float* ent_w = (const float*)d_in[6];
  const float* ent_b = (const float*)d_in[7];
  const float* bW = (const float*)d_in[8];
  const float* bb = (const float*)d_in[9];
  const float* sW1 = (const float*)d_in[10];
  const float* sb1 = (const float*)d_in[11];
  const float* sW2 = (const float*)d_in[12];
  const float* sb2 = (const float*)d_in[13];
  const float* sW3 = (const float*)d_in[14];
  const float* sb3 = (const float*)d_in[15];
  const float* dW1 = (const float*)d_in[16];
  const float* db1 = (const float*)d_in[17];
  const float* dW2 = (const float*)d_in[18];
  const float* db2 = (const float*)d_in[19];
  const float* dW3 = (const float*)d_in[20];
  const float* db3 = (const float*)d_in[21];
  float* out = (float*)d_out;
  float* ws = (float*)d_ws;

  hipLaunchKernelGGL(k_pre, dim3(658), dim3(256), 0, stream, emb, ae_w, ae_b,
                     ent_w, ent_b, bW, sW1, dW1, ws, out);
  hipLaunchKernelGGL(k_main, dim3(1664), dim3(256), 0, stream, atom_types,
                     positions, bonds, emb, bb, sb1, sW2, sb2, sW3, sb3, db1,
                     dW2, db2, dW3, db3, ws, out);
}